// Round 1
// 478.013 us; speedup vs baseline: 1.0601x; 1.0601x over previous
//
#include <hip/hip_runtime.h>
#include <hip/hip_bf16.h>
#include <cstdint>

// Problem constants (b=2, s=4096, dim=1024, heads=64, dim_head=64)
#define M_TOK 8192
#define DIM   1024
#define INNER 4096
#define HEADS 64
#define DH    64
#define QSCALE 0.125f      // 64^-0.5
#define EPS    1e-6f

typedef __hip_bfloat16 bf16;
typedef __bf16 bf16x8_t __attribute__((ext_vector_type(8)));
typedef float f32x4_t __attribute__((ext_vector_type(4)));

__device__ __forceinline__ float bfbits2f(unsigned short u) {
  return __uint_as_float(((unsigned)u) << 16);
}
__device__ __forceinline__ unsigned short f2bfbits(float f) {
  __hip_bfloat16 h = __float2bfloat16(f);
  unsigned short u;
  __builtin_memcpy(&u, &h, 2);
  return u;
}

// async global->LDS, 16B per lane. LDS dst must be wave-uniform base + lane*16.
__device__ __forceinline__ void load_lds16(const void* g, void* l) {
  __builtin_amdgcn_global_load_lds(
      (__attribute__((address_space(1))) void*)g,
      (__attribute__((address_space(3))) void*)l, 16, 0, 0);
}

// XCD-aware block swizzle: XCD x owns M-tiles [x*gy/8, (x+1)*gy/8), N-major
// within the XCD. (R3: cut gemm_out FETCH_SIZE 270->66 MB.)
__device__ __forceinline__ void swizzle_xy(int& bx, int& by) {
  const int gx = gridDim.x, gy = gridDim.y;
  const int id  = blockIdx.x + gx * blockIdx.y;
  const int per = gy >> 3;          // M-tiles per XCD (gy % 8 == 0)
  const int xcd = id & 7;
  const int s   = id >> 3;
  by = xcd * per + (s % per);
  bx = s / per;
}

// ---------------------------------------------------------------------------
// cast x (fp32) -> bf16, same layout. One float4 per thread.
// ---------------------------------------------------------------------------
__global__ __launch_bounds__(256) void castx_kernel(
    const float* __restrict__ x, unsigned short* __restrict__ xb, int n4)
{
  const int i = blockIdx.x * 256 + threadIdx.x;
  if (i < n4) {
    const float4 v = reinterpret_cast<const float4*>(x)[i];
    ushort4 o;
    o.x = f2bfbits(v.x); o.y = f2bfbits(v.y);
    o.z = f2bfbits(v.z); o.w = f2bfbits(v.w);
    reinterpret_cast<ushort4*>(xb)[i] = o;
  }
}

// ---------------------------------------------------------------------------
// transpose-cast: W [R][C] fp32 -> Wt [C][R] bf16.  32x32 LDS tiles.
// ---------------------------------------------------------------------------
__global__ __launch_bounds__(256) void tcast_kernel(
    const float* __restrict__ W, unsigned short* __restrict__ Wt, int R, int C)
{
  __shared__ float tile[32][33];
  const int bx = blockIdx.x * 32;   // C offset
  const int by = blockIdx.y * 32;   // R offset
  const int tx = threadIdx.x & 31;
  const int ty = threadIdx.x >> 5;  // 0..7
#pragma unroll
  for (int k = 0; k < 4; ++k)
    tile[ty + k * 8][tx] = W[(size_t)(by + ty + k * 8) * C + bx + tx];
  __syncthreads();
#pragma unroll
  for (int k = 0; k < 4; ++k)
    Wt[(size_t)(bx + ty + k * 8) * R + by + tx] = f2bfbits(tile[tx][ty + k * 8]);
}

// Dual version: z=0 -> W0 into Wt[0:C*R), z=1 -> W1 into Wt[C*R:2*C*R).
__global__ __launch_bounds__(256) void tcast_dual_kernel(
    const float* __restrict__ W0, const float* __restrict__ W1,
    unsigned short* __restrict__ Wt, int R, int C)
{
  __shared__ float tile[32][33];
  const float* W = blockIdx.z ? W1 : W0;
  unsigned short* dst = Wt + (size_t)blockIdx.z * R * C;
  const int bx = blockIdx.x * 32;
  const int by = blockIdx.y * 32;
  const int tx = threadIdx.x & 31;
  const int ty = threadIdx.x >> 5;
#pragma unroll
  for (int k = 0; k < 4; ++k)
    tile[ty + k * 8][tx] = W[(size_t)(by + ty + k * 8) * C + bx + tx];
  __syncthreads();
#pragma unroll
  for (int k = 0; k < 4; ++k)
    dst[(size_t)(bx + ty + k * 8) * R + by + tx] = f2bfbits(tile[tx][ty + k * 8]);
}

// ---------------------------------------------------------------------------
// 256x256 8-phase GEMM (T2+T3+T4+T5). 512 thr = 8 waves (2M x 4N), BK=64.
// LDS 128 KB: As[2][256x64] + Bs[2][256x64] (double-buffered).
// LDS swizzle: row = 8 x 16B chunks, stored slot = chunk ^ (row&7)
//   (proven conflict-free in prior rounds: SQ_LDS_BANK_CONFLICT == 0).
//
// Pipeline invariants (derived; keep when editing):
//  - half-tile = 128 rows of one matrix = 2 global_load_lds / thread.
//  - tile T's A staged at T-2 ph2/ph3 into As[T&1]; B staged at T-1 ph0/ph1
//    into Bs[T&1].  All ds_reads of tile T retire by end of ph1 (A) /
//    ph2 (B), so those writes never collide with live reads (barrier-fenced).
//  - at tile T ph3 (after MFMA, before closing barrier): this wave's
//    outstanding loads are, oldest first: T+1.B0, T+1.B1, T+2.A0, T+2.A1.
//    s_waitcnt vmcnt(4) => all of tile T+1 resident, 2 half-tiles in flight.
//    Never drains to 0 in steady state (T4).  Tail (T >= NT-2): vmcnt(0).
// MODE: 0 identity, 1 relu, 2 relu*QSCALE.  DUAL: split-N K/V epilogue.
// ---------------------------------------------------------------------------
__device__ __forceinline__ void stage_half(
    const unsigned short* __restrict__ G, unsigned short* L,
    int rowbase, int k0, int K, int h, int tid)
{
#pragma unroll
  for (int j = 0; j < 2; ++j) {
    const int q  = h * 1024 + j * 512 + tid;     // chunk index in 256x64 tile
    const int r  = q >> 3;                       // row 0..255
    const int cg = (tid & 7) ^ (r & 7);          // global k-chunk (inverse swz)
    load_lds16(&G[(size_t)(rowbase + r) * K + k0 + cg * 8], &L[q * 8]);
  }
}

template <int MODE, int DUAL>
__global__ __launch_bounds__(512, 2) void gemm256(
    const unsigned short* __restrict__ A,   // [M][K] bf16
    const unsigned short* __restrict__ Bt,  // [N][K] bf16 (B transposed)
    unsigned short* __restrict__ C0,
    unsigned short* __restrict__ C1,
    int N, int K)
{
  __shared__ __align__(16) unsigned short As[2][256 * 64];  // 64 KB
  __shared__ __align__(16) unsigned short Bs[2][256 * 64];  // 64 KB

  int bxi, byi;
  swizzle_xy(bxi, byi);
  const int tid  = threadIdx.x;
  const int bm   = byi * 256;
  const int bn   = bxi * 256;
  const int lane = tid & 63;
  const int w    = tid >> 6;
  const int wm   = (w >> 2) * 128;   // wave M offset (0/128)
  const int wn   = (w & 3) * 64;     // wave N offset (0/64/128/192)
  const int quad = lane >> 4;
  const int l15  = lane & 15;

  f32x4_t acc[8][4];
#pragma unroll
  for (int mt = 0; mt < 8; ++mt)
#pragma unroll
    for (int nt = 0; nt < 4; ++nt) acc[mt][nt] = (f32x4_t){0.f, 0.f, 0.f, 0.f};

  const int NT = K >> 6;

  // ---- prologue: tile0 A+B, tile1 A. vmcnt(4) -> tile0 resident. ----
  stage_half(A,  As[0], bm, 0,  K, 0, tid);
  stage_half(A,  As[0], bm, 0,  K, 1, tid);
  stage_half(Bt, Bs[0], bn, 0,  K, 0, tid);
  stage_half(Bt, Bs[0], bn, 0,  K, 1, tid);
  stage_half(A,  As[1], bm, 64, K, 0, tid);
  stage_half(A,  As[1], bm, 64, K, 1, tid);
  asm volatile("s_waitcnt vmcnt(4)" ::: "memory");
  __builtin_amdgcn_sched_barrier(0);
  __builtin_amdgcn_s_barrier();
  __builtin_amdgcn_sched_barrier(0);

  bf16x8_t af[8][2], bfr[4][2];

  for (int T = 0; T < NT; ++T) {
    const int c = T & 1;
    const unsigned short* Ac = As[c];
    const unsigned short* Bc = Bs[c];
    unsigned short* Bnx = Bs[c ^ 1];   // tile T+1 B lands here
    unsigned short* Anx = As[c];       // tile T+2 A lands here (A reads done ph1)
    const int kB = (T + 1) * 64;
    const int kA = (T + 2) * 64;
    const bool pB = (T + 1 < NT);
    const bool pA = (T + 2 < NT);

    // ===== phase 0: read A m0-3 + B n0-1 (12 b128); stage T+1 B.h0; Q(m0-3,n0-1)
#pragma unroll
    for (int mt = 0; mt < 4; ++mt) {
      const int r = wm + mt * 16 + l15;
#pragma unroll
      for (int kt = 0; kt < 2; ++kt) {
        const int s = (kt * 4 + quad) ^ (r & 7);
        af[mt][kt] = *reinterpret_cast<const bf16x8_t*>(&Ac[r * 64 + s * 8]);
      }
    }
#pragma unroll
    for (int nt = 0; nt < 2; ++nt) {
      const int r = wn + nt * 16 + l15;
#pragma unroll
      for (int kt = 0; kt < 2; ++kt) {
        const int s = (kt * 4 + quad) ^ (r & 7);
        bfr[nt][kt] = *reinterpret_cast<const bf16x8_t*>(&Bc[r * 64 + s * 8]);
      }
    }
    if (pB) stage_half(Bt, Bnx, bn, kB, K, 0, tid);
    __builtin_amdgcn_sched_barrier(0);
    __builtin_amdgcn_s_barrier();
    __builtin_amdgcn_sched_barrier(0);
    __builtin_amdgcn_s_setprio(1);
#pragma unroll
    for (int mt = 0; mt < 4; ++mt)
#pragma unroll
      for (int nt = 0; nt < 2; ++nt) {
        acc[mt][nt] = __builtin_amdgcn_mfma_f32_16x16x32_bf16(
            af[mt][0], bfr[nt][0], acc[mt][nt], 0, 0, 0);
        acc[mt][nt] = __builtin_amdgcn_mfma_f32_16x16x32_bf16(
            af[mt][1], bfr[nt][1], acc[mt][nt], 0, 0, 0);
      }
    __builtin_amdgcn_s_setprio(0);
    __builtin_amdgcn_sched_barrier(0);
    __builtin_amdgcn_s_barrier();
    __builtin_amdgcn_sched_barrier(0);

    // ===== phase 1: read A m4-7 (8 b128); stage T+1 B.h1; Q(m4-7,n0-1)
#pragma unroll
    for (int mt = 4; mt < 8; ++mt) {
      const int r = wm + mt * 16 + l15;
#pragma unroll
      for (int kt = 0; kt < 2; ++kt) {
        const int s = (kt * 4 + quad) ^ (r & 7);
        af[mt][kt] = *reinterpret_cast<const bf16x8_t*>(&Ac[r * 64 + s * 8]);
      }
    }
    if (pB) stage_half(Bt, Bnx, bn, kB, K, 1, tid);
    __builtin_amdgcn_sched_barrier(0);
    __builtin_amdgcn_s_barrier();
    __builtin_amdgcn_sched_barrier(0);
    __builtin_amdgcn_s_setprio(1);
#pragma unroll
    for (int mt = 4; mt < 8; ++mt)
#pragma unroll
      for (int nt = 0; nt < 2; ++nt) {
        acc[mt][nt] = __builtin_amdgcn_mfma_f32_16x16x32_bf16(
            af[mt][0], bfr[nt][0], acc[mt][nt], 0, 0, 0);
        acc[mt][nt] = __builtin_amdgcn_mfma_f32_16x16x32_bf16(
            af[mt][1], bfr[nt][1], acc[mt][nt], 0, 0, 0);
      }
    __builtin_amdgcn_s_setprio(0);
    __builtin_amdgcn_sched_barrier(0);
    __builtin_amdgcn_s_barrier();
    __builtin_amdgcn_sched_barrier(0);

    // ===== phase 2: read B n2-3 (4 b128); stage T+2 A.h0; Q(m0-3,n2-3)
#pragma unroll
    for (int nt = 2; nt < 4; ++nt) {
      const int r = wn + nt * 16 + l15;
#pragma unroll
      for (int kt = 0; kt < 2; ++kt) {
        const int s = (kt * 4 + quad) ^ (r & 7);
        bfr[nt][kt] = *reinterpret_cast<const bf16x8_t*>(&Bc[r * 64 + s * 8]);
      }
    }
    if (pA) stage_half(A, Anx, bm, kA, K, 0, tid);
    __builtin_amdgcn_sched_barrier(0);
    __builtin_amdgcn_s_barrier();
    __builtin_amdgcn_sched_barrier(0);
    __builtin_amdgcn_s_setprio(1);
#pragma unroll
    for (int mt = 0; mt < 4; ++mt)
#pragma unroll
      for (int nt = 2; nt < 4; ++nt) {
        acc[mt][nt] = __builtin_amdgcn_mfma_f32_16x16x32_bf16(
            af[mt][0], bfr[nt][0], acc[mt][nt], 0, 0, 0);
        acc[mt][nt] = __builtin_amdgcn_mfma_f32_16x16x32_bf16(
            af[mt][1], bfr[nt][1], acc[mt][nt], 0, 0, 0);
      }
    __builtin_amdgcn_s_setprio(0);
    __builtin_amdgcn_sched_barrier(0);
    __builtin_amdgcn_s_barrier();
    __builtin_amdgcn_sched_barrier(0);

    // ===== phase 3: stage T+2 A.h1; Q(m4-7,n2-3); counted vmcnt; barrier
    if (pA) stage_half(A, Anx, bm, kA, K, 1, tid);
    __builtin_amdgcn_sched_barrier(0);
    __builtin_amdgcn_s_barrier();
    __builtin_amdgcn_sched_barrier(0);
    __builtin_amdgcn_s_setprio(1);
#pragma unroll
    for (int mt = 4; mt < 8; ++mt)
#pragma unroll
      for (int nt = 2; nt < 4; ++nt) {
        acc[mt][nt] = __builtin_amdgcn_mfma_f32_16x16x32_bf16(
            af[mt][0], bfr[nt][0], acc[mt][nt], 0, 0, 0);
        acc[mt][nt] = __builtin_amdgcn_mfma_f32_16x16x32_bf16(
            af[mt][1], bfr[nt][1], acc[mt][nt], 0, 0, 0);
      }
    __builtin_amdgcn_s_setprio(0);
    __builtin_amdgcn_sched_barrier(0);
    if (T < NT - 2) {
      asm volatile("s_waitcnt vmcnt(4)" ::: "memory");  // T+1 resident; T+2.A in flight
    } else {
      asm volatile("s_waitcnt vmcnt(0)" ::: "memory");  // tail drain
    }
    __builtin_amdgcn_sched_barrier(0);
    __builtin_amdgcn_s_barrier();
    __builtin_amdgcn_sched_barrier(0);
  }

  // ---- epilogue ----
  if (DUAL) {
    const bool isK = (bn < 4096);
    unsigned short* __restrict__ C = isK ? C0 : C1;
    const int bnc = bn & 4095;
#pragma unroll
    for (int mt = 0; mt < 8; ++mt)
#pragma unroll
      for (int i = 0; i < 4; ++i) {
        const size_t rowg = (size_t)(bm + wm + mt * 16 + quad * 4 + i);
#pragma unroll
        for (int nt = 0; nt < 4; ++nt) {
          float v = acc[mt][nt][i];
          if (isK) v = fmaxf(v, 0.f);
          C[rowg * 4096 + bnc + wn + nt * 16 + l15] = f2bfbits(v);
        }
      }
  } else {
#pragma unroll
    for (int mt = 0; mt < 8; ++mt)
#pragma unroll
      for (int i = 0; i < 4; ++i) {
        const size_t rowg = (size_t)(bm + wm + mt * 16 + quad * 4 + i);
#pragma unroll
        for (int nt = 0; nt < 4; ++nt) {
          float v = acc[mt][nt][i];
          if (MODE >= 1) v = fmaxf(v, 0.f);
          if (MODE == 2) v *= QSCALE;
          C0[rowg * (size_t)N + bn + wn + nt * 16 + l15] = f2bfbits(v);
        }
      }
  }
}

// ---------------------------------------------------------------------------
// Output MFMA GEMM: out[M,N] = A[M,K] @ Bt[N,K]^T + bias[N], fp32 out.
// 128(M) x 64(N) tile, BK=64 (R4-validated). N=1024 is too narrow for 256^2
// tiles (128 blocks would idle half the chip), so this keeps the old shape.
// ---------------------------------------------------------------------------
__global__ __launch_bounds__(256) void gemm_out_bf16(
    const unsigned short* __restrict__ A,   // [M][K] bf16
    const unsigned short* __restrict__ Bt,  // [N][K] bf16
    const float* __restrict__ bias,
    float* __restrict__ out, int M, int N, int K)
{
  __shared__ __align__(16) unsigned short As[128 * 64];  // 16 KB
  __shared__ __align__(16) unsigned short Bs[64 * 64];   //  8 KB

  int bxi, byi;
  swizzle_xy(bxi, byi);
  const int tid  = threadIdx.x;
  const int bm   = byi * 128;
  const int bn   = bxi * 64;
  const int lane = tid & 63;
  const int w    = tid >> 6;
  const int wm   = (w & 1) * 64;
  const int wn   = (w >> 1) * 32;
  const int quad = lane >> 4;
  const int l15  = lane & 15;

  f32x4_t acc[4][2];
#pragma unroll
  for (int mt = 0; mt < 4; ++mt)
#pragma unroll
    for (int nt = 0; nt < 2; ++nt) acc[mt][nt] = (f32x4_t){0.f, 0.f, 0.f, 0.f};

  int qa[4], ra[4], ca[4];
#pragma unroll
  for (int j = 0; j < 4; ++j) {
    qa[j] = tid + 256 * j;
    ra[j] = qa[j] >> 3;
    ca[j] = (qa[j] & 7) ^ (ra[j] & 7);
  }
  int qb[2], rb[2], cb[2];
#pragma unroll
  for (int j = 0; j < 2; ++j) {
    qb[j] = tid + 256 * j;
    rb[j] = qb[j] >> 3;
    cb[j] = (qb[j] & 7) ^ (rb[j] & 7);
  }

  for (int k0 = 0; k0 < K; k0 += 64) {
    __syncthreads();
#pragma unroll
    for (int j = 0; j < 4; ++j)
      load_lds16(&A[(size_t)(bm + ra[j]) * K + k0 + ca[j] * 8], &As[qa[j] * 8]);
#pragma unroll
    for (int j = 0; j < 2; ++j)
      load_lds16(&Bt[(size_t)(bn + rb[j]) * K + k0 + cb[j] * 8], &Bs[qb[j] * 8]);
    __syncthreads();

    bf16x8_t af[4][2], bfr[2][2];
#pragma unroll
    for (int mt = 0; mt < 4; ++mt) {
      const int r = wm + mt * 16 + l15;
#pragma unroll
      for (int kt = 0; kt < 2; ++kt) {
        const int slot = (kt * 4 + quad) ^ (r & 7);
        af[mt][kt] = *reinterpret_cast<const bf16x8_t*>(&As[r * 64 + slot * 8]);
      }
    }
#pragma unroll
    for (int nt = 0; nt < 2; ++nt) {
      const int r = wn + nt * 16 + l15;
#pragma unroll
      for (int kt = 0; kt < 2; ++kt) {
        const int slot = (kt * 4 + quad) ^ (r & 7);
        bfr[nt][kt] = *reinterpret_cast<const bf16x8_t*>(&Bs[r * 64 + slot * 8]);
      }
    }
#pragma unroll
    for (int mt = 0; mt < 4; ++mt)
#pragma unroll
      for (int nt = 0; nt < 2; ++nt) {
        acc[mt][nt] = __builtin_amdgcn_mfma_f32_16x16x32_bf16(
            af[mt][0], bfr[nt][0], acc[mt][nt], 0, 0, 0);
        acc[mt][nt] = __builtin_amdgcn_mfma_f32_16x16x32_bf16(
            af[mt][1], bfr[nt][1], acc[mt][nt], 0, 0, 0);
      }
  }

#pragma unroll
  for (int mt = 0; mt < 4; ++mt)
#pragma unroll
    for (int i = 0; i < 4; ++i) {
      const size_t rowg = (size_t)(bm + wm + mt * 16 + quad * 4 + i);
#pragma unroll
      for (int nt = 0; nt < 2; ++nt) {
        const int colg = bn + wn + nt * 16 + l15;
        out[rowg * N + colg] = acc[mt][nt][i] + bias[colg];
      }
    }
}

// ---------------------------------------------------------------------------
// ksum[t][d] = sum_i K[t][i*64+d].  One wave per token, 4 tokens/block.
// ---------------------------------------------------------------------------
__global__ __launch_bounds__(256) void ksum_kernel(
    const unsigned short* __restrict__ Kb, float* __restrict__ ks)
{
  const int t = blockIdx.x * 4 + (threadIdx.x >> 6);
  const int j = threadIdx.x & 63;
  const uint4* row = reinterpret_cast<const uint4*>(Kb + (size_t)t * INNER);
  float s[8] = {0.f, 0.f, 0.f, 0.f, 0.f, 0.f, 0.f, 0.f};
#pragma unroll
  for (int m = 0; m < 8; ++m) {
    const uint4 u = row[j + 64 * m];
    s[0] += __uint_as_float((u.x & 0xFFFFu) << 16);
    s[1] += __uint_as_float(u.x & 0xFFFF0000u);
    s[2] += __uint_as_float((u.y & 0xFFFFu) << 16);
    s[3] += __uint_as_float(u.y & 0xFFFF0000u);
    s[4] += __uint_as_float((u.z & 0xFFFFu) << 16);
    s[5] += __uint_as_float(u.z & 0xFFFF0000u);
    s[6] += __uint_as_float((u.w & 0xFFFFu) << 16);
    s[7] += __uint_as_float(u.w & 0xFFFF0000u);
  }
#pragma unroll
  for (int off = 8; off < 64; off <<= 1)
#pragma unroll
    for (int e = 0; e < 8; ++e) s[e] += __shfl_xor(s[e], off, 64);
  if (j < 8) {
    float4* dst = reinterpret_cast<float4*>(ks + t * 64 + j * 8);
    float4 lo, hi;
    lo.x = s[0]; lo.y = s[1]; lo.z = s[2]; lo.w = s[3];
    hi.x = s[4]; hi.y = s[5]; hi.z = s[6]; hi.w = s[7];
    dst[0] = lo; dst[1] = hi;
  }
}

// ---------------------------------------------------------------------------
// MFMA attention: one wave per token, 4 tokens/block, zero LDS (R3-verified).
// ---------------------------------------------------------------------------
__global__ __launch_bounds__(256) void attn_mfma(
    const unsigned short* __restrict__ Qb, const unsigned short* __restrict__ Vb,
    const float* __restrict__ ksum, unsigned short* __restrict__ Ab)
{
  const int t    = blockIdx.x * 4 + (threadIdx.x >> 6);
  const int lane = threadIdx.x & 63;
  const int l15  = lane & 15;
  const int quad = lane >> 4;
  const size_t base = (size_t)t * INNER;

  union VU { bf16x8_t v; unsigned short u[8]; };

  float ksv[2][8];
#pragma unroll
  for (int kt = 0; kt < 2; ++kt) {
    const float4* p = reinterpret_cast<const float4*>(ksum + t * 64 + kt * 32 + quad * 8);
    const float4 a = p[0], b = p[1];
    ksv[kt][0] = a.x; ksv[kt][1] = a.y; ksv[kt][2] = a.z; ksv[kt][3] = a.w;
    ksv[kt][4] = b.x; ksv[kt][5] = b.y; ksv[kt][6] = b.z; ksv[kt][7] = b.w;
  }

  bf16x8_t vs[4][2];
#pragma unroll
  for (int nt = 0; nt < 4; ++nt)
#pragma unroll
    for (int kt = 0; kt < 2; ++kt) {
      VU vr, vo;
      vr.v = *reinterpret_cast<const bf16x8_t*>(
          Vb + base + (size_t)(nt * 16 + l15) * 64 + kt * 32 + quad * 8);
#pragma unroll
      for (int j = 0; j < 8; ++j)
        vo.u[j] = f2bfbits(bfbits2f(vr.u[j]) * ksv[kt][j]);
      vs[nt][kt] = vo.v;
    }

  bf16x8_t qf[4][2];
  float qn[4] = {0.f, 0.f, 0.f, 0.f};
#pragma unroll
  for (int mt = 0; mt < 4; ++mt)
#pragma unroll
    for (int kt = 0; kt < 2; ++kt) {
      VU qr;
      qr.v = *reinterpret_cast<const bf16x8_t*>(
          Qb + base + (size_t)(mt * 16 + l15) * 64 + kt * 32 + quad * 8);
      qf[mt][kt] = qr.v;
#pragma unroll
      for (int j = 0; j < 8; ++j)
        qn[mt] += bfbits2f(qr.u[j]) * ksv[kt][j];
    }
#pragma unroll
  for (int mt = 0; mt < 4; ++mt) {
    qn[mt] += __shfl_xor(qn[mt], 16, 64);
    qn[mt] += __shfl_xor(qn[mt], 32, 64);
  }

  f32x4_t acc[4][4];
#pragma unroll
  for (int mt = 0; mt < 4; ++mt)
#pragma unroll
    for (int nt = 0; nt < 4; ++nt) acc[mt][nt] = (f32x4_t){0.f, 0.f, 0.f, 0.f};

#pragma unroll
  for (int mt = 0; mt < 4; ++mt)
#pragma unroll
    for (int nt = 0; nt < 4; ++nt) {
      acc[mt][nt] = __builtin_amdgcn_mfma_f32_16x16x32_bf16(
          qf[mt][0], vs[nt][0], acc[mt][nt], 0, 0, 0);
      acc[mt][nt] = __builtin_amdgcn_mfma_f32_16x16x32_bf16(
          qf[mt][1], vs[nt][1], acc[mt][nt], 0, 0, 0);
    }

#pragma unroll
  for (int mt = 0; mt < 4; ++mt)
#pragma unroll
    for (int i = 0; i < 4; ++i) {
      const float inv = 1.f / (__shfl(qn[mt], quad * 4 + i, 64) + EPS);
      const size_t roff = base + (size_t)(mt * 16 + quad * 4 + i) * 64;
#pragma unroll
      for (int nt = 0; nt < 4; ++nt)
        Ab[roff + nt * 16 + l15] = f2bfbits(acc[mt][nt][i] * inv);
    }
}

// ---------------------------------------------------------------------------
// Buffers (ws = 130 MB):
//  ws   @0      : K (transient) -> Q -> A (in place)
//  ws   @64MB   : V ; first 8MB reused for Wo^T after attn
//  ws   @128MB  : ksum (fp32 8192x64, 2MB)
//  d_out@0      : Xb (bf16 8192x1024, 16MB)       — dead before gemm_out writes
//  d_out@16MB   : WtKV (bf16 8192x1024, 16MB)     — then WqT (8MB)
// ---------------------------------------------------------------------------
extern "C" void kernel_launch(void* const* d_in, const int* in_sizes, int n_in,
                              void* d_out, int out_size, void* d_ws, size_t ws_size,
                              hipStream_t stream)
{
  const float* x  = (const float*)d_in[0];
  const float* Wq = (const float*)d_in[1];
  const float* Wk = (const float*)d_in[2];
  const float* Wv = (const float*)d_in[3];
  const float* Wo = (const float*)d_in[4];
  const float* bo = (const float*)d_in[5];
  float* out = (float*)d_out;

  uint8_t* ws = (uint8_t*)d_ws;
  const size_t HALF = (size_t)M_TOK * INNER * sizeof(bf16);  // 64 MB
  unsigned short* KQA = (unsigned short*)ws;            // K -> Q -> A
  unsigned short* Vb  = (unsigned short*)(ws + HALF);   // V ; then Wo^T
  float* ks           = (float*)(ws + 2 * HALF);

  unsigned short* Xb   = (unsigned short*)d_out;                           // 16 MB
  unsigned short* WtKV = (unsigned short*)((uint8_t*)d_out + (16u << 20)); // 16 MB
  unsigned short* WqT  = WtKV;   // reused after gemm_kv
  unsigned short* Wot  = Vb;     // Wo^T over dead V (after attn)

  const dim3 blk(256);
  const dim3 blk512(512);

  castx_kernel<<<dim3(M_TOK * DIM / 4 / 256), blk, 0, stream>>>(
      x, Xb, M_TOK * DIM / 4);

  // Wk^T and Wv^T stacked -> WtKV [8192][1024]
  tcast_dual_kernel<<<dim3(INNER / 32, DIM / 32, 2), blk, 0, stream>>>(
      Wk, Wv, WtKV, DIM, INNER);

  // fused K+V projection: 256^2 8-phase, DUAL epilogue (relu->K, id->V)
  gemm256<0, 1><<<dim3(2 * INNER / 256, M_TOK / 256), blk512, 0, stream>>>(
      Xb, WtKV, KQA, Vb, 2 * INNER, DIM);

  ksum_kernel<<<dim3(M_TOK / 4), blk, 0, stream>>>(KQA, ks);

  tcast_kernel<<<dim3(INNER / 32, DIM / 32), blk, 0, stream>>>(
      Wq, WqT, DIM, INNER);

  // Q projection: relu * QSCALE, overwrites dead K
  gemm256<2, 0><<<dim3(INNER / 256, M_TOK / 256), blk512, 0, stream>>>(
      Xb, WqT, KQA, nullptr, INNER, DIM);

  attn_mfma<<<dim3(M_TOK / 4), blk, 0, stream>>>(KQA, Vb, ks, KQA);  // A in place

  tcast_kernel<<<dim3(DIM / 32, INNER / 32), blk, 0, stream>>>(
      Wo, Wot, INNER, DIM);  // over dead V

  gemm_out_bf16<<<dim3(DIM / 64, M_TOK / 128), blk, 0, stream>>>(
      KQA, Wot, bo, out, M_TOK, DIM, INNER);
}

// Round 2
// 469.140 us; speedup vs baseline: 1.0801x; 1.0189x over previous
//
#include <hip/hip_runtime.h>
#include <hip/hip_bf16.h>
#include <cstdint>

// Problem constants (b=2, s=4096, dim=1024, heads=64, dim_head=64)
#define M_TOK 8192
#define DIM   1024
#define INNER 4096
#define HEADS 64
#define DH    64
#define QSCALE 0.125f      // 64^-0.5
#define EPS    1e-6f

typedef __hip_bfloat16 bf16;
typedef __bf16 bf16x8_t __attribute__((ext_vector_type(8)));
typedef float f32x4_t __attribute__((ext_vector_type(4)));

__device__ __forceinline__ float bfbits2f(unsigned short u) {
  return __uint_as_float(((unsigned)u) << 16);
}
__device__ __forceinline__ unsigned short f2bfbits(float f) {
  __hip_bfloat16 h = __float2bfloat16(f);
  unsigned short u;
  __builtin_memcpy(&u, &h, 2);
  return u;
}

// async global->LDS, 16B per lane. LDS dst must be wave-uniform base + lane*16.
__device__ __forceinline__ void load_lds16(const void* g, void* l) {
  __builtin_amdgcn_global_load_lds(
      (__attribute__((address_space(1))) void*)g,
      (__attribute__((address_space(3))) void*)l, 16, 0, 0);
}

// XCD-aware block swizzle: XCD x owns M-tiles [x*gy/8, (x+1)*gy/8), N-major
// within the XCD. (R3: cut gemm_out FETCH_SIZE 270->66 MB.)
__device__ __forceinline__ void swizzle_xy(int& bx, int& by) {
  const int gx = gridDim.x, gy = gridDim.y;
  const int id  = blockIdx.x + gx * blockIdx.y;
  const int per = gy >> 3;          // M-tiles per XCD (gy % 8 == 0)
  const int xcd = id & 7;
  const int s   = id >> 3;
  by = xcd * per + (s % per);
  bx = s / per;
}

// ---------------------------------------------------------------------------
// cast x (fp32) -> bf16, same layout. One float4 per thread.
// ---------------------------------------------------------------------------
__global__ __launch_bounds__(256) void castx_kernel(
    const float* __restrict__ x, unsigned short* __restrict__ xb, int n4)
{
  const int i = blockIdx.x * 256 + threadIdx.x;
  if (i < n4) {
    const float4 v = reinterpret_cast<const float4*>(x)[i];
    ushort4 o;
    o.x = f2bfbits(v.x); o.y = f2bfbits(v.y);
    o.z = f2bfbits(v.z); o.w = f2bfbits(v.w);
    reinterpret_cast<ushort4*>(xb)[i] = o;
  }
}

// ---------------------------------------------------------------------------
// transpose-cast: W [R][C] fp32 -> Wt [C][R] bf16.  32x32 LDS tiles.
// ---------------------------------------------------------------------------
__global__ __launch_bounds__(256) void tcast_kernel(
    const float* __restrict__ W, unsigned short* __restrict__ Wt, int R, int C)
{
  __shared__ float tile[32][33];
  const int bx = blockIdx.x * 32;   // C offset
  const int by = blockIdx.y * 32;   // R offset
  const int tx = threadIdx.x & 31;
  const int ty = threadIdx.x >> 5;  // 0..7
#pragma unroll
  for (int k = 0; k < 4; ++k)
    tile[ty + k * 8][tx] = W[(size_t)(by + ty + k * 8) * C + bx + tx];
  __syncthreads();
#pragma unroll
  for (int k = 0; k < 4; ++k)
    Wt[(size_t)(bx + ty + k * 8) * R + by + tx] = f2bfbits(tile[tx][ty + k * 8]);
}

// Dual version: z=0 -> W0 into Wt[0:C*R), z=1 -> W1 into Wt[C*R:2*C*R).
__global__ __launch_bounds__(256) void tcast_dual_kernel(
    const float* __restrict__ W0, const float* __restrict__ W1,
    unsigned short* __restrict__ Wt, int R, int C)
{
  __shared__ float tile[32][33];
  const float* W = blockIdx.z ? W1 : W0;
  unsigned short* dst = Wt + (size_t)blockIdx.z * R * C;
  const int bx = blockIdx.x * 32;
  const int by = blockIdx.y * 32;
  const int tx = threadIdx.x & 31;
  const int ty = threadIdx.x >> 5;
#pragma unroll
  for (int k = 0; k < 4; ++k)
    tile[ty + k * 8][tx] = W[(size_t)(by + ty + k * 8) * C + bx + tx];
  __syncthreads();
#pragma unroll
  for (int k = 0; k < 4; ++k)
    dst[(size_t)(bx + ty + k * 8) * R + by + tx] = f2bfbits(tile[tx][ty + k * 8]);
}

// ---------------------------------------------------------------------------
// 256x256 8-phase GEMM (T2+T3+T4+T5). 512 thr = 8 waves (2M x 4N), BK=64.
// LDS 128 KB: As[2][256x64] + Bs[2][256x64] (double-buffered).
// LDS swizzle: row = 8 x 16B chunks, stored slot = chunk ^ (row&7)
//   (proven conflict-free: SQ_LDS_BANK_CONFLICT == 0 in R1 counters).
//
// R2 change: NO sched_barrier(0) pins (m141 lesson: pinning defeats the
// compiler's ds_read / global_load_lds / MFMA interleave, which is the whole
// point of the 8-phase schedule — m196).  Ordering correctness relies on:
//   - asm vmcnt with "memory" clobber at each tile end (fences tile T reads
//     against tile T-1 staging drain),
//   - conservative LDS aliasing (compiler won't reorder LDS writes vs reads),
//   - raw s_barrier for cross-wave phase sync.
//
// Pipeline invariants (derived; keep when editing):
//  - half-tile = 128 rows of one matrix = 2 global_load_lds / thread.
//  - tile T's A staged at T-2 ph2/ph3 into As[T&1]; B staged at T-1 ph0/ph1
//    into Bs[T&1].  All ds_reads of tile T's A retire by end of ph1, B by
//    ph2, so those writes never collide with live reads (barrier-fenced).
//  - at tile T ph3 end: this wave's outstanding loads, oldest first:
//    T+1.B0, T+1.B1, T+2.A0, T+2.A1.  s_waitcnt vmcnt(4) => all of tile T+1
//    resident, 2 half-tiles (T+2.A) still in flight.  Never drains to 0 in
//    steady state (T4).  Tail (T >= NT-2): vmcnt(0).
// MODE: 0 identity, 1 relu, 2 relu*QSCALE.  DUAL: split-N K/V epilogue.
// ---------------------------------------------------------------------------
__device__ __forceinline__ void stage_half(
    const unsigned short* __restrict__ G, unsigned short* L,
    int rowbase, int k0, int K, int h, int tid)
{
#pragma unroll
  for (int j = 0; j < 2; ++j) {
    const int q  = h * 1024 + j * 512 + tid;     // chunk index in 256x64 tile
    const int r  = q >> 3;                       // row 0..255
    const int cg = (tid & 7) ^ (r & 7);          // global k-chunk (inverse swz)
    load_lds16(&G[(size_t)(rowbase + r) * K + k0 + cg * 8], &L[q * 8]);
  }
}

template <int MODE, int DUAL>
__global__ __launch_bounds__(512, 2) void gemm256(
    const unsigned short* __restrict__ A,   // [M][K] bf16
    const unsigned short* __restrict__ Bt,  // [N][K] bf16 (B transposed)
    unsigned short* __restrict__ C0,
    unsigned short* __restrict__ C1,
    int N, int K)
{
  __shared__ __align__(16) unsigned short As[2][256 * 64];  // 64 KB
  __shared__ __align__(16) unsigned short Bs[2][256 * 64];  // 64 KB

  int bxi, byi;
  swizzle_xy(bxi, byi);
  const int tid  = threadIdx.x;
  const int bm   = byi * 256;
  const int bn   = bxi * 256;
  const int lane = tid & 63;
  const int w    = tid >> 6;
  const int wm   = (w >> 2) * 128;   // wave M offset (0/128)
  const int wn   = (w & 3) * 64;     // wave N offset (0/64/128/192)
  const int quad = lane >> 4;
  const int l15  = lane & 15;

  f32x4_t acc[8][4];
#pragma unroll
  for (int mt = 0; mt < 8; ++mt)
#pragma unroll
    for (int nt = 0; nt < 4; ++nt) acc[mt][nt] = (f32x4_t){0.f, 0.f, 0.f, 0.f};

  const int NT = K >> 6;

  // ---- prologue: tile0 A+B, tile1 A. vmcnt(4) -> tile0 resident. ----
  stage_half(A,  As[0], bm, 0,  K, 0, tid);
  stage_half(A,  As[0], bm, 0,  K, 1, tid);
  stage_half(Bt, Bs[0], bn, 0,  K, 0, tid);
  stage_half(Bt, Bs[0], bn, 0,  K, 1, tid);
  stage_half(A,  As[1], bm, 64, K, 0, tid);
  stage_half(A,  As[1], bm, 64, K, 1, tid);
  asm volatile("s_waitcnt vmcnt(4)" ::: "memory");
  __builtin_amdgcn_s_barrier();

  bf16x8_t af[8][2], bfr[4][2];

  for (int T = 0; T < NT; ++T) {
    const int c = T & 1;
    const unsigned short* Ac = As[c];
    const unsigned short* Bc = Bs[c];
    unsigned short* Bnx = Bs[c ^ 1];   // tile T+1 B lands here
    unsigned short* Anx = As[c];       // tile T+2 A lands here (A reads done ph1)
    const int kB = (T + 1) * 64;
    const int kA = (T + 2) * 64;
    const bool pB = (T + 1 < NT);
    const bool pA = (T + 2 < NT);

    // ===== phase 0: read A m0-3 + B n0-1 (12 b128); stage T+1 B.h0; Q(m0-3,n0-1)
#pragma unroll
    for (int mt = 0; mt < 4; ++mt) {
      const int r = wm + mt * 16 + l15;
#pragma unroll
      for (int kt = 0; kt < 2; ++kt) {
        const int s = (kt * 4 + quad) ^ (r & 7);
        af[mt][kt] = *reinterpret_cast<const bf16x8_t*>(&Ac[r * 64 + s * 8]);
      }
    }
#pragma unroll
    for (int nt = 0; nt < 2; ++nt) {
      const int r = wn + nt * 16 + l15;
#pragma unroll
      for (int kt = 0; kt < 2; ++kt) {
        const int s = (kt * 4 + quad) ^ (r & 7);
        bfr[nt][kt] = *reinterpret_cast<const bf16x8_t*>(&Bc[r * 64 + s * 8]);
      }
    }
    if (pB) stage_half(Bt, Bnx, bn, kB, K, 0, tid);
    __builtin_amdgcn_s_barrier();
    __builtin_amdgcn_s_setprio(1);
#pragma unroll
    for (int mt = 0; mt < 4; ++mt)
#pragma unroll
      for (int nt = 0; nt < 2; ++nt) {
        acc[mt][nt] = __builtin_amdgcn_mfma_f32_16x16x32_bf16(
            af[mt][0], bfr[nt][0], acc[mt][nt], 0, 0, 0);
        acc[mt][nt] = __builtin_amdgcn_mfma_f32_16x16x32_bf16(
            af[mt][1], bfr[nt][1], acc[mt][nt], 0, 0, 0);
      }
    __builtin_amdgcn_s_setprio(0);
    __builtin_amdgcn_s_barrier();

    // ===== phase 1: read A m4-7 (8 b128); stage T+1 B.h1; Q(m4-7,n0-1)
#pragma unroll
    for (int mt = 4; mt < 8; ++mt) {
      const int r = wm + mt * 16 + l15;
#pragma unroll
      for (int kt = 0; kt < 2; ++kt) {
        const int s = (kt * 4 + quad) ^ (r & 7);
        af[mt][kt] = *reinterpret_cast<const bf16x8_t*>(&Ac[r * 64 + s * 8]);
      }
    }
    if (pB) stage_half(Bt, Bnx, bn, kB, K, 1, tid);
    __builtin_amdgcn_s_barrier();
    __builtin_amdgcn_s_setprio(1);
#pragma unroll
    for (int mt = 4; mt < 8; ++mt)
#pragma unroll
      for (int nt = 0; nt < 2; ++nt) {
        acc[mt][nt] = __builtin_amdgcn_mfma_f32_16x16x32_bf16(
            af[mt][0], bfr[nt][0], acc[mt][nt], 0, 0, 0);
        acc[mt][nt] = __builtin_amdgcn_mfma_f32_16x16x32_bf16(
            af[mt][1], bfr[nt][1], acc[mt][nt], 0, 0, 0);
      }
    __builtin_amdgcn_s_setprio(0);
    __builtin_amdgcn_s_barrier();

    // ===== phase 2: read B n2-3 (4 b128); stage T+2 A.h0; Q(m0-3,n2-3)
#pragma unroll
    for (int nt = 2; nt < 4; ++nt) {
      const int r = wn + nt * 16 + l15;
#pragma unroll
      for (int kt = 0; kt < 2; ++kt) {
        const int s = (kt * 4 + quad) ^ (r & 7);
        bfr[nt][kt] = *reinterpret_cast<const bf16x8_t*>(&Bc[r * 64 + s * 8]);
      }
    }
    if (pA) stage_half(A, Anx, bm, kA, K, 0, tid);
    __builtin_amdgcn_s_barrier();
    __builtin_amdgcn_s_setprio(1);
#pragma unroll
    for (int mt = 0; mt < 4; ++mt)
#pragma unroll
      for (int nt = 2; nt < 4; ++nt) {
        acc[mt][nt] = __builtin_amdgcn_mfma_f32_16x16x32_bf16(
            af[mt][0], bfr[nt][0], acc[mt][nt], 0, 0, 0);
        acc[mt][nt] = __builtin_amdgcn_mfma_f32_16x16x32_bf16(
            af[mt][1], bfr[nt][1], acc[mt][nt], 0, 0, 0);
      }
    __builtin_amdgcn_s_setprio(0);
    __builtin_amdgcn_s_barrier();

    // ===== phase 3: stage T+2 A.h1; Q(m4-7,n2-3); counted vmcnt; barrier
    if (pA) stage_half(A, Anx, bm, kA, K, 1, tid);
    __builtin_amdgcn_s_barrier();
    __builtin_amdgcn_s_setprio(1);
#pragma unroll
    for (int mt = 4; mt < 8; ++mt)
#pragma unroll
      for (int nt = 2; nt < 4; ++nt) {
        acc[mt][nt] = __builtin_amdgcn_mfma_f32_16x16x32_bf16(
            af[mt][0], bfr[nt][0], acc[mt][nt], 0, 0, 0);
        acc[mt][nt] = __builtin_amdgcn_mfma_f32_16x16x32_bf16(
            af[mt][1], bfr[nt][1], acc[mt][nt], 0, 0, 0);
      }
    __builtin_amdgcn_s_setprio(0);
    if (T < NT - 2) {
      asm volatile("s_waitcnt vmcnt(4)" ::: "memory");  // T+1 resident; T+2.A in flight
    } else {
      asm volatile("s_waitcnt vmcnt(0)" ::: "memory");  // tail drain
    }
    __builtin_amdgcn_s_barrier();
  }

  // ---- epilogue ----
  if (DUAL) {
    const bool isK = (bn < 4096);
    unsigned short* __restrict__ C = isK ? C0 : C1;
    const int bnc = bn & 4095;
#pragma unroll
    for (int mt = 0; mt < 8; ++mt)
#pragma unroll
      for (int i = 0; i < 4; ++i) {
        const size_t rowg = (size_t)(bm + wm + mt * 16 + quad * 4 + i);
#pragma unroll
        for (int nt = 0; nt < 4; ++nt) {
          float v = acc[mt][nt][i];
          if (isK) v = fmaxf(v, 0.f);
          C[rowg * 4096 + bnc + wn + nt * 16 + l15] = f2bfbits(v);
        }
      }
  } else {
#pragma unroll
    for (int mt = 0; mt < 8; ++mt)
#pragma unroll
      for (int i = 0; i < 4; ++i) {
        const size_t rowg = (size_t)(bm + wm + mt * 16 + quad * 4 + i);
#pragma unroll
        for (int nt = 0; nt < 4; ++nt) {
          float v = acc[mt][nt][i];
          if (MODE >= 1) v = fmaxf(v, 0.f);
          if (MODE == 2) v *= QSCALE;
          C0[rowg * (size_t)N + bn + wn + nt * 16 + l15] = f2bfbits(v);
        }
      }
  }
}

// ---------------------------------------------------------------------------
// Output MFMA GEMM: out[M,N] = A[M,K] @ Bt[N,K]^T + bias[N], fp32 out.
// 128(M) x 64(N) tile, BK=64 (R4-validated). N=1024 is too narrow for 256^2
// tiles (128 blocks would idle half the chip), so this keeps the old shape.
// ---------------------------------------------------------------------------
__global__ __launch_bounds__(256) void gemm_out_bf16(
    const unsigned short* __restrict__ A,   // [M][K] bf16
    const unsigned short* __restrict__ Bt,  // [N][K] bf16
    const float* __restrict__ bias,
    float* __restrict__ out, int M, int N, int K)
{
  __shared__ __align__(16) unsigned short As[128 * 64];  // 16 KB
  __shared__ __align__(16) unsigned short Bs[64 * 64];   //  8 KB

  int bxi, byi;
  swizzle_xy(bxi, byi);
  const int tid  = threadIdx.x;
  const int bm   = byi * 128;
  const int bn   = bxi * 64;
  const int lane = tid & 63;
  const int w    = tid >> 6;
  const int wm   = (w & 1) * 64;
  const int wn   = (w >> 1) * 32;
  const int quad = lane >> 4;
  const int l15  = lane & 15;

  f32x4_t acc[4][2];
#pragma unroll
  for (int mt = 0; mt < 4; ++mt)
#pragma unroll
    for (int nt = 0; nt < 2; ++nt) acc[mt][nt] = (f32x4_t){0.f, 0.f, 0.f, 0.f};

  int qa[4], ra[4], ca[4];
#pragma unroll
  for (int j = 0; j < 4; ++j) {
    qa[j] = tid + 256 * j;
    ra[j] = qa[j] >> 3;
    ca[j] = (qa[j] & 7) ^ (ra[j] & 7);
  }
  int qb[2], rb[2], cb[2];
#pragma unroll
  for (int j = 0; j < 2; ++j) {
    qb[j] = tid + 256 * j;
    rb[j] = qb[j] >> 3;
    cb[j] = (qb[j] & 7) ^ (rb[j] & 7);
  }

  for (int k0 = 0; k0 < K; k0 += 64) {
    __syncthreads();
#pragma unroll
    for (int j = 0; j < 4; ++j)
      load_lds16(&A[(size_t)(bm + ra[j]) * K + k0 + ca[j] * 8], &As[qa[j] * 8]);
#pragma unroll
    for (int j = 0; j < 2; ++j)
      load_lds16(&Bt[(size_t)(bn + rb[j]) * K + k0 + cb[j] * 8], &Bs[qb[j] * 8]);
    __syncthreads();

    bf16x8_t af[4][2], bfr[2][2];
#pragma unroll
    for (int mt = 0; mt < 4; ++mt) {
      const int r = wm + mt * 16 + l15;
#pragma unroll
      for (int kt = 0; kt < 2; ++kt) {
        const int slot = (kt * 4 + quad) ^ (r & 7);
        af[mt][kt] = *reinterpret_cast<const bf16x8_t*>(&As[r * 64 + slot * 8]);
      }
    }
#pragma unroll
    for (int nt = 0; nt < 2; ++nt) {
      const int r = wn + nt * 16 + l15;
#pragma unroll
      for (int kt = 0; kt < 2; ++kt) {
        const int slot = (kt * 4 + quad) ^ (r & 7);
        bfr[nt][kt] = *reinterpret_cast<const bf16x8_t*>(&Bs[r * 64 + slot * 8]);
      }
    }
#pragma unroll
    for (int mt = 0; mt < 4; ++mt)
#pragma unroll
      for (int nt = 0; nt < 2; ++nt) {
        acc[mt][nt] = __builtin_amdgcn_mfma_f32_16x16x32_bf16(
            af[mt][0], bfr[nt][0], acc[mt][nt], 0, 0, 0);
        acc[mt][nt] = __builtin_amdgcn_mfma_f32_16x16x32_bf16(
            af[mt][1], bfr[nt][1], acc[mt][nt], 0, 0, 0);
      }
  }

#pragma unroll
  for (int mt = 0; mt < 4; ++mt)
#pragma unroll
    for (int i = 0; i < 4; ++i) {
      const size_t rowg = (size_t)(bm + wm + mt * 16 + quad * 4 + i);
#pragma unroll
      for (int nt = 0; nt < 2; ++nt) {
        const int colg = bn + wn + nt * 16 + l15;
        out[rowg * N + colg] = acc[mt][nt][i] + bias[colg];
      }
    }
}

// ---------------------------------------------------------------------------
// ksum[t][d] = sum_i K[t][i*64+d].  One wave per token, 4 tokens/block.
// ---------------------------------------------------------------------------
__global__ __launch_bounds__(256) void ksum_kernel(
    const unsigned short* __restrict__ Kb, float* __restrict__ ks)
{
  const int t = blockIdx.x * 4 + (threadIdx.x >> 6);
  const int j = threadIdx.x & 63;
  const uint4* row = reinterpret_cast<const uint4*>(Kb + (size_t)t * INNER);
  float s[8] = {0.f, 0.f, 0.f, 0.f, 0.f, 0.f, 0.f, 0.f};
#pragma unroll
  for (int m = 0; m < 8; ++m) {
    const uint4 u = row[j + 64 * m];
    s[0] += __uint_as_float((u.x & 0xFFFFu) << 16);
    s[1] += __uint_as_float(u.x & 0xFFFF0000u);
    s[2] += __uint_as_float((u.y & 0xFFFFu) << 16);
    s[3] += __uint_as_float(u.y & 0xFFFF0000u);
    s[4] += __uint_as_float((u.z & 0xFFFFu) << 16);
    s[5] += __uint_as_float(u.z & 0xFFFF0000u);
    s[6] += __uint_as_float((u.w & 0xFFFFu) << 16);
    s[7] += __uint_as_float(u.w & 0xFFFF0000u);
  }
#pragma unroll
  for (int off = 8; off < 64; off <<= 1)
#pragma unroll
    for (int e = 0; e < 8; ++e) s[e] += __shfl_xor(s[e], off, 64);
  if (j < 8) {
    float4* dst = reinterpret_cast<float4*>(ks + t * 64 + j * 8);
    float4 lo, hi;
    lo.x = s[0]; lo.y = s[1]; lo.z = s[2]; lo.w = s[3];
    hi.x = s[4]; hi.y = s[5]; hi.z = s[6]; hi.w = s[7];
    dst[0] = lo; dst[1] = hi;
  }
}

// ---------------------------------------------------------------------------
// MFMA attention: one wave per token, 4 tokens/block, zero LDS (R3-verified).
// ---------------------------------------------------------------------------
__global__ __launch_bounds__(256) void attn_mfma(
    const unsigned short* __restrict__ Qb, const unsigned short* __restrict__ Vb,
    const float* __restrict__ ksum, unsigned short* __restrict__ Ab)
{
  const int t    = blockIdx.x * 4 + (threadIdx.x >> 6);
  const int lane = threadIdx.x & 63;
  const int l15  = lane & 15;
  const int quad = lane >> 4;
  const size_t base = (size_t)t * INNER;

  union VU { bf16x8_t v; unsigned short u[8]; };

  float ksv[2][8];
#pragma unroll
  for (int kt = 0; kt < 2; ++kt) {
    const float4* p = reinterpret_cast<const float4*>(ksum + t * 64 + kt * 32 + quad * 8);
    const float4 a = p[0], b = p[1];
    ksv[kt][0] = a.x; ksv[kt][1] = a.y; ksv[kt][2] = a.z; ksv[kt][3] = a.w;
    ksv[kt][4] = b.x; ksv[kt][5] = b.y; ksv[kt][6] = b.z; ksv[kt][7] = b.w;
  }

  bf16x8_t vs[4][2];
#pragma unroll
  for (int nt = 0; nt < 4; ++nt)
#pragma unroll
    for (int kt = 0; kt < 2; ++kt) {
      VU vr, vo;
      vr.v = *reinterpret_cast<const bf16x8_t*>(
          Vb + base + (size_t)(nt * 16 + l15) * 64 + kt * 32 + quad * 8);
#pragma unroll
      for (int j = 0; j < 8; ++j)
        vo.u[j] = f2bfbits(bfbits2f(vr.u[j]) * ksv[kt][j]);
      vs[nt][kt] = vo.v;
    }

  bf16x8_t qf[4][2];
  float qn[4] = {0.f, 0.f, 0.f, 0.f};
#pragma unroll
  for (int mt = 0; mt < 4; ++mt)
#pragma unroll
    for (int kt = 0; kt < 2; ++kt) {
      VU qr;
      qr.v = *reinterpret_cast<const bf16x8_t*>(
          Qb + base + (size_t)(mt * 16 + l15) * 64 + kt * 32 + quad * 8);
      qf[mt][kt] = qr.v;
#pragma unroll
      for (int j = 0; j < 8; ++j)
        qn[mt] += bfbits2f(qr.u[j]) * ksv[kt][j];
    }
#pragma unroll
  for (int mt = 0; mt < 4; ++mt) {
    qn[mt] += __shfl_xor(qn[mt], 16, 64);
    qn[mt] += __shfl_xor(qn[mt], 32, 64);
  }

  f32x4_t acc[4][4];
#pragma unroll
  for (int mt = 0; mt < 4; ++mt)
#pragma unroll
    for (int nt = 0; nt < 4; ++nt) acc[mt][nt] = (f32x4_t){0.f, 0.f, 0.f, 0.f};

#pragma unroll
  for (int mt = 0; mt < 4; ++mt)
#pragma unroll
    for (int nt = 0; nt < 4; ++nt) {
      acc[mt][nt] = __builtin_amdgcn_mfma_f32_16x16x32_bf16(
          qf[mt][0], vs[nt][0], acc[mt][nt], 0, 0, 0);
      acc[mt][nt] = __builtin_amdgcn_mfma_f32_16x16x32_bf16(
          qf[mt][1], vs[nt][1], acc[mt][nt], 0, 0, 0);
    }

#pragma unroll
  for (int mt = 0; mt < 4; ++mt)
#pragma unroll
    for (int i = 0; i < 4; ++i) {
      const float inv = 1.f / (__shfl(qn[mt], quad * 4 + i, 64) + EPS);
      const size_t roff = base + (size_t)(mt * 16 + quad * 4 + i) * 64;
#pragma unroll
      for (int nt = 0; nt < 4; ++nt)
        Ab[roff + nt * 16 + l15] = f2bfbits(acc[mt][nt][i] * inv);
    }
}

// ---------------------------------------------------------------------------
// Buffers (ws = 130 MB):
//  ws   @0      : K (transient) -> Q -> A (in place)
//  ws   @64MB   : V ; first 8MB reused for Wo^T after attn
//  ws   @128MB  : ksum (fp32 8192x64, 2MB)
//  d_out@0      : Xb (bf16 8192x1024, 16MB)       — dead before gemm_out writes
//  d_out@16MB   : WtKV (bf16 8192x1024, 16MB)     — then WqT (8MB)
// ---------------------------------------------------------------------------
extern "C" void kernel_launch(void* const* d_in, const int* in_sizes, int n_in,
                              void* d_out, int out_size, void* d_ws, size_t ws_size,
                              hipStream_t stream)
{
  const float* x  = (const float*)d_in[0];
  const float* Wq = (const float*)d_in[1];
  const float* Wk = (const float*)d_in[2];
  const float* Wv = (const float*)d_in[3];
  const float* Wo = (const float*)d_in[4];
  const float* bo = (const float*)d_in[5];
  float* out = (float*)d_out;

  uint8_t* ws = (uint8_t*)d_ws;
  const size_t HALF = (size_t)M_TOK * INNER * sizeof(bf16);  // 64 MB
  unsigned short* KQA = (unsigned short*)ws;            // K -> Q -> A
  unsigned short* Vb  = (unsigned short*)(ws + HALF);   // V ; then Wo^T
  float* ks           = (float*)(ws + 2 * HALF);

  unsigned short* Xb   = (unsigned short*)d_out;                           // 16 MB
  unsigned short* WtKV = (unsigned short*)((uint8_t*)d_out + (16u << 20)); // 16 MB
  unsigned short* WqT  = WtKV;   // reused after gemm_kv
  unsigned short* Wot  = Vb;     // Wo^T over dead V (after attn)

  const dim3 blk(256);
  const dim3 blk512(512);

  castx_kernel<<<dim3(M_TOK * DIM / 4 / 256), blk, 0, stream>>>(
      x, Xb, M_TOK * DIM / 4);

  // Wk^T and Wv^T stacked -> WtKV [8192][1024]
  tcast_dual_kernel<<<dim3(INNER / 32, DIM / 32, 2), blk, 0, stream>>>(
      Wk, Wv, WtKV, DIM, INNER);

  // fused K+V projection: 256^2 8-phase, DUAL epilogue (relu->K, id->V)
  gemm256<0, 1><<<dim3(2 * INNER / 256, M_TOK / 256), blk512, 0, stream>>>(
      Xb, WtKV, KQA, Vb, 2 * INNER, DIM);

  ksum_kernel<<<dim3(M_TOK / 4), blk, 0, stream>>>(KQA, ks);

  tcast_kernel<<<dim3(INNER / 32, DIM / 32), blk, 0, stream>>>(
      Wq, WqT, DIM, INNER);

  // Q projection: relu * QSCALE, overwrites dead K
  gemm256<2, 0><<<dim3(INNER / 256, M_TOK / 256), blk512, 0, stream>>>(
      Xb, WqT, KQA, nullptr, INNER, DIM);

  attn_mfma<<<dim3(M_TOK / 4), blk, 0, stream>>>(KQA, Vb, ks, KQA);  // A in place

  tcast_kernel<<<dim3(DIM / 32, INNER / 32), blk, 0, stream>>>(
      Wo, Wot, INNER, DIM);  // over dead V

  gemm_out_bf16<<<dim3(DIM / 64, M_TOK / 128), blk, 0, stream>>>(
      KQA, Wot, bo, out, M_TOK, DIM, INNER);
}